// Round 4
// baseline (429.970 us; speedup 1.0000x reference)
//
#include <hip/hip_runtime.h>
#include <hip/hip_bf16.h>
#include <math.h>

constexpr int C_DIM = 256;
constexpr int MROWS = 25088;   // B*H*W
constexpr int HID   = 1024;

typedef float  f32x4 __attribute__((ext_vector_type(4)));
typedef short  s16x8 __attribute__((ext_vector_type(8)));

__device__ __forceinline__ ushort f2bf(float f) {
    __hip_bfloat16 h = __float2bfloat16(f);
    return *reinterpret_cast<ushort*>(&h);
}
__device__ __forceinline__ unsigned pkbf2(float a, float b) {
    __hip_bfloat162 h = __float22bfloat162_rn(float2{a, b});
    return *reinterpret_cast<unsigned*>(&h);
}
__device__ __forceinline__ float bf2f(ushort u) {
    return __uint_as_float(((unsigned)u) << 16);
}

// async global->LDS, 16B per lane; dest = wave-uniform base + lane*16
typedef const __attribute__((address_space(1))) unsigned guint;
typedef __attribute__((address_space(3))) unsigned luint;
__device__ __forceinline__ void gload16(const void* g, void* l) {
    __builtin_amdgcn_global_load_lds((guint*)g, (luint*)l, 16, 0, 0);
}

// ---------------- LayerNorm: one wave per row, bf16 out ----------------
__global__ __launch_bounds__(256) void ln_kernel(
    const float* __restrict__ x, const float* __restrict__ g,
    const float* __restrict__ b, ushort* __restrict__ out)
{
    int wv = threadIdx.x >> 6, lane = threadIdx.x & 63;
    size_t row = (size_t)blockIdx.x * 4 + wv;
    float4 v = *(const float4*)(x + row * 256 + lane * 4);
    float s1 = v.x + v.y + v.z + v.w;
    float s2 = v.x*v.x + v.y*v.y + v.z*v.z + v.w*v.w;
    #pragma unroll
    for (int d = 1; d < 64; d <<= 1) {
        s1 += __shfl_xor(s1, d);
        s2 += __shfl_xor(s2, d);
    }
    float mu  = s1 * (1.0f / 256.0f);
    float var = s2 * (1.0f / 256.0f) - mu * mu;
    float inv = rsqrtf(var + 1e-5f);
    float4 gv = *(const float4*)(g + lane * 4);
    float4 bv = *(const float4*)(b + lane * 4);
    uint2 o;
    o.x = pkbf2((v.x - mu) * inv * gv.x + bv.x, (v.y - mu) * inv * gv.y + bv.y);
    o.y = pkbf2((v.z - mu) * inv * gv.z + bv.z, (v.w - mu) * inv * gv.w + bv.w);
    *(uint2*)(out + row * 256 + lane * 4) = o;
}

// ---------------- fused weight transpose + cvt: all four weights ----------------
__global__ __launch_bounds__(256) void wcvt_all(
    const float* __restrict__ w0, const float* __restrict__ w1,
    const float* __restrict__ w2, const float* __restrict__ w3,
    ushort* __restrict__ o0, ushort* __restrict__ o1,
    ushort* __restrict__ o2, ushort* __restrict__ o3)
{
    __shared__ ushort tile[64][65];
    int bid = blockIdx.x;
    const float* w; ushort* o; int K, N, tIdx;
    if (bid < 48)       { w = w0; o = o0; K = 256;  N = 768;  tIdx = bid; }
    else if (bid < 64)  { w = w1; o = o1; K = 256;  N = 256;  tIdx = bid - 48; }
    else if (bid < 128) { w = w2; o = o2; K = 256;  N = 1024; tIdx = bid - 64; }
    else                { w = w3; o = o3; K = 1024; N = 256;  tIdx = bid - 128; }
    int nx = N >> 6;
    int bx = tIdx % nx, by = tIdx / nx;
    int n0 = bx * 64, k0 = by * 64;
    int c = threadIdx.x & 63, rr = threadIdx.x >> 6;
    #pragma unroll
    for (int i = 0; i < 64; i += 4) {
        int r = i + rr;
        tile[r][c] = f2bf(w[(size_t)(k0 + r) * N + n0 + c]);
    }
    __syncthreads();
    #pragma unroll
    for (int i = 0; i < 64; i += 4) {
        int r = i + rr;
        o[(size_t)(n0 + r) * K + k0 + c] = tile[c][r];
    }
}

// ---------------- bf16 MFMA GEMM (m97 structure): C = A[M,K] @ Bt[N,K]^T ----------------
// FUSE: 0 = bf16 out; 1 = +bias +residual(f32), f32 out; 2 = +bias +GELU, bf16 out
template<int FUSE>
__global__ __launch_bounds__(256) void gemm_bf16(
    const ushort* __restrict__ A, const ushort* __restrict__ Bt,
    const float* __restrict__ bias, const float* res,
    void* Cout, int M, int N, int K)
{
    __shared__ ushort As[128 * 32];
    __shared__ ushort Bs[128 * 32];
    int tid  = threadIdx.x;
    int lane = tid & 63, wv = tid >> 6;
    int lr = lane & 15, lg = lane >> 4;
    int row0 = blockIdx.y * 128, col0 = blockIdx.x * 128;
    int wr = wv >> 1, wc = wv & 1;

    f32x4 acc[4][4];
    #pragma unroll
    for (int m = 0; m < 4; ++m)
        #pragma unroll
        for (int n = 0; n < 4; ++n)
            acc[m][n] = (f32x4){0.f, 0.f, 0.f, 0.f};

    int srow = wv * 32 + (lane >> 2);
    const ushort* gA  = A  + (size_t)(row0 + srow) * K + (lane & 3) * 8;
    const ushort* gA2 = gA + (size_t)16 * K;
    const ushort* gB  = Bt + (size_t)(col0 + srow) * K + (lane & 3) * 8;
    const ushort* gB2 = gB + (size_t)16 * K;
    ushort* lA  = &As[(wv * 32 +  0) * 32];
    ushort* lA2 = &As[(wv * 32 + 16) * 32];
    ushort* lB  = &Bs[(wv * 32 +  0) * 32];
    ushort* lB2 = &Bs[(wv * 32 + 16) * 32];

    for (int k0 = 0; k0 < K; k0 += 32) {
        gload16(gA  + k0, lA);
        gload16(gA2 + k0, lA2);
        gload16(gB  + k0, lB);
        gload16(gB2 + k0, lB2);
        __syncthreads();
        s16x8 af[4], bfg[4];
        #pragma unroll
        for (int m = 0; m < 4; ++m)
            af[m] = *(const s16x8*)&As[(wr * 64 + m * 16 + lr) * 32 + lg * 8];
        #pragma unroll
        for (int n = 0; n < 4; ++n)
            bfg[n] = *(const s16x8*)&Bs[(wc * 64 + n * 16 + lr) * 32 + lg * 8];
        #pragma unroll
        for (int m = 0; m < 4; ++m)
            #pragma unroll
            for (int n = 0; n < 4; ++n)
                acc[m][n] = __builtin_amdgcn_mfma_f32_16x16x32_bf16(af[m], bfg[n], acc[m][n], 0, 0, 0);
        __syncthreads();
    }

    int grow0 = row0 + wr * 64;
    int gcol0 = col0 + wc * 64;
    #pragma unroll
    for (int m = 0; m < 4; ++m) {
        #pragma unroll
        for (int n = 0; n < 4; ++n) {
            int gcol = gcol0 + n * 16 + lr;
            float bv = (FUSE >= 1) ? bias[gcol] : 0.0f;
            #pragma unroll
            for (int r = 0; r < 4; ++r) {
                int grow = grow0 + m * 16 + lg * 4 + r;
                float v = acc[m][n][r] + bv;
                if (FUSE == 2) v = 0.5f * v * (1.0f + erff(v * 0.70710678118654752f));
                if (FUSE == 1) {
                    v += res[(size_t)grow * N + gcol];
                    ((float*)Cout)[(size_t)grow * N + gcol] = v;
                } else {
                    ((ushort*)Cout)[(size_t)grow * N + gcol] = f2bf(v);
                }
            }
        }
    }
}

// ---------------- MFMA windowed attention + fused LePE (swapped-QK, no-max softmax) ----
// grid 512 = 2 branch x 64 win x 4 head; 512 threads = 8 waves.
// Per-chunk compute-and-consume (rolled loop) — NO S register blocking (spills, r3 lesson).
__device__ __forceinline__ int wrow(int branch, int b, int wi, int n) {
    if (branch) return b * 3136 + wi * 392 + n;
    int ii = n / 7;
    return b * 3136 + ii * 56 + wi * 7 + (n - ii * 7);
}

__global__ __launch_bounds__(512, 4) void attn_kernel(
    const ushort* __restrict__ qkv,   // bf16 [M,768]
    const float* __restrict__ c0w, const float* __restrict__ c0b,
    const float* __restrict__ c1w, const float* __restrict__ c1b,
    ushort* __restrict__ att)         // bf16 [M,256]
{
    __shared__ ushort Kh[2 * 416 * 16];   // two d-half planes [416 k][16 d]  26,624 B
    __shared__ ushort Vt[32][424];        // V^T [d][k]                       27,136 B
    __shared__ ushort Pl[8][16][40];      // per-wave P chunk [16 q][32 k]    10,240 B
    __shared__ float  CwS[9][32];         // LePE conv weights for this (branch,head)
    __shared__ float  CbS[32];

    int bid    = blockIdx.x;
    int branch = bid >> 8;
    int rem    = bid & 255;
    int head   = rem & 3;
    int win    = rem >> 2;
    int b  = win >> 3, wi = win & 7;
    int c0 = branch * 128 + head * 32;
    const float* cw = branch ? c1w : c0w;
    const float* cb = branch ? c1b : c0b;
    int tid = threadIdx.x;

    // stage conv weights/bias
    if (tid < 288) {
        int tap = tid >> 5, d = tid & 31;
        CwS[tap][d] = cw[tap * 128 + head * 32 + d];
    } else if (tid < 320) {
        CbS[tid - 288] = cb[head * 32 + (tid - 288)];
    }
    // ---- stage K into two 16-wide planes (rows >=392 zero) ----
    for (int e = tid; e < 1664; e += 512) {
        int n = e >> 2, quad = e & 3;
        uint4 v = make_uint4(0u, 0u, 0u, 0u);
        if (n < 392) {
            int gr = wrow(branch, b, wi, n);
            v = *(const uint4*)(qkv + (size_t)gr * 768 + 256 + c0 + quad * 8);
        }
        *(uint4*)&Kh[(quad >> 1) * 6656 + n * 16 + (quad & 1) * 8] = v;
    }
    // ---- stage V transposed ----
    for (int e = tid; e < 1568; e += 512) {
        int n = e >> 2, quad = e & 3;
        int gr = wrow(branch, b, wi, n);
        uint4 v = *(const uint4*)(qkv + (size_t)gr * 768 + 512 + c0 + quad * 8);
        const ushort* us = (const ushort*)&v;
        #pragma unroll
        for (int j = 0; j < 8; ++j) Vt[quad * 8 + j][n] = us[j];
    }
    for (int e = tid; e < 1024; e += 512) {
        int d = e >> 5, k = 392 + (e & 31);
        Vt[d][k] = 0;
    }
    __syncthreads();

    int wv = tid >> 6, lane = tid & 63;
    int lr = lane & 15, lg = lane >> 4;
    constexpr float kSc = 0.17677669529663689f * 1.4426950408889634f;  // scale * log2(e)
    ushort* Pw = &Pl[wv][0][0];
    int Hsp = branch ? 7 : 56, Wsp = branch ? 56 : 7;
    const ushort* Kbase = &Kh[(lg >> 1) * 6656 + lr * 16 + (lg & 1) * 8];

    for (int qt = wv; qt < 25; qt += 8) {
        int q0 = qt * 16;
        int qn = q0 + lr; if (qn > 391) qn = 391;
        int qr = wrow(branch, b, wi, qn);
        s16x8 qf = *(const s16x8*)(qkv + (size_t)qr * 768 + c0 + lg * 8);

        f32x4 o0 = {0.f, 0.f, 0.f, 0.f}, o1 = {0.f, 0.f, 0.f, 0.f};
        float psum = 0.0f;

        auto do_chunk = [&](int c, bool last) {
            f32x4 z = {0.f, 0.f, 0.f, 0.f};
            s16x8 kf0 = *(const s16x8*)&Kbase[(c * 32)      * 16];
            s16x8 kf1 = *(const s16x8*)&Kbase[(c * 32 + 16) * 16];
            f32x4 s0 = __builtin_amdgcn_mfma_f32_16x16x32_bf16(kf0, qf, z, 0, 0, 0);
            f32x4 s1 = __builtin_amdgcn_mfma_f32_16x16x32_bf16(kf1, qf, z, 0, 0, 0);
            float p[2][4];
            #pragma unroll
            for (int r = 0; r < 4; ++r) {
                p[0][r] = exp2f(s0[r] * kSc);
                p[1][r] = exp2f(s1[r] * kSc);
            }
            if (last) {   // mask padding keys (k >= 392): chunk 12 covers 384..415
                #pragma unroll
                for (int t = 0; t < 2; ++t)
                    #pragma unroll
                    for (int r = 0; r < 4; ++r) {
                        int kk = 384 + t * 16 + lg * 4 + r;
                        if (kk >= 392) p[t][r] = 0.0f;
                    }
            }
            #pragma unroll
            for (int t = 0; t < 2; ++t)
                #pragma unroll
                for (int r = 0; r < 4; ++r) psum += p[t][r];
            uint2 w0, w1;
            w0.x = pkbf2(p[0][0], p[0][1]); w0.y = pkbf2(p[0][2], p[0][3]);
            w1.x = pkbf2(p[1][0], p[1][1]); w1.y = pkbf2(p[1][2], p[1][3]);
            *(uint2*)&Pw[lr * 40 + lg * 4]      = w0;
            *(uint2*)&Pw[lr * 40 + 16 + lg * 4] = w1;
            s16x8 pf = *(const s16x8*)&Pw[lr * 40 + lg * 8];
            s16x8 v0 = *(const s16x8*)&Vt[lr][c * 32 + lg * 8];
            s16x8 v1 = *(const s16x8*)&Vt[16 + lr][c * 32 + lg * 8];
            o0 = __builtin_amdgcn_mfma_f32_16x16x32_bf16(pf, v0, o0, 0, 0, 0);
            o1 = __builtin_amdgcn_mfma_f32_16x16x32_bf16(pf, v1, o1, 0, 0, 0);
        };

        for (int c = 0; c < 12; ++c) do_chunk(c, false);
        do_chunk(12, true);

        // finalize l per q (lane holds partial for q = lr): sum over the 4 lg groups
        psum += __shfl_xor(psum, 16);
        psum += __shfl_xor(psum, 32);
        // redistribute 1/l to output rows q = lg*4+r
        float linv[4];
        #pragma unroll
        for (int r = 0; r < 4; ++r)
            linv[r] = 1.0f / __shfl(psum, lg * 4 + r);
        #pragma unroll
        for (int r = 0; r < 4; ++r) { o0[r] *= linv[r]; o1[r] *= linv[r]; }

        // LePE conv + bias + store
        #pragma unroll
        for (int r = 0; r < 4; ++r) {
            int q = q0 + lg * 4 + r;
            if (q >= 392) continue;
            int ii = branch ? (q / 56) : (q / 7);
            int jj = q - ii * Wsp;
            float a0 = o0[r], a1 = o1[r];
            #pragma unroll
            for (int kh = 0; kh < 3; ++kh) {
                int i2 = ii + kh - 1;
                if ((unsigned)i2 >= (unsigned)Hsp) continue;
                #pragma unroll
                for (int kw = 0; kw < 3; ++kw) {
                    int j2 = jj + kw - 1;
                    if ((unsigned)j2 >= (unsigned)Wsp) continue;
                    int pos = i2 * Wsp + j2;
                    a0 += CwS[kh * 3 + kw][lr]      * bf2f(Vt[lr][pos]);
                    a1 += CwS[kh * 3 + kw][16 + lr] * bf2f(Vt[16 + lr][pos]);
                }
            }
            a0 += CbS[lr]; a1 += CbS[16 + lr];
            int gr = wrow(branch, b, wi, q);
            att[(size_t)gr * 256 + branch * 128 + head * 32 + lr]      = f2bf(a0);
            att[(size_t)gr * 256 + branch * 128 + head * 32 + 16 + lr] = f2bf(a1);
        }
    }
}

// ---------------- launcher ----------------
extern "C" void kernel_launch(void* const* d_in, const int* in_sizes, int n_in,
                              void* d_out, int out_size, void* d_ws, size_t ws_size,
                              hipStream_t stream)
{
    const float* x      = (const float*)d_in[0];
    const float* n1g    = (const float*)d_in[3];
    const float* n1b    = (const float*)d_in[4];
    const float* qkv_w  = (const float*)d_in[5];
    const float* proj_w = (const float*)d_in[6];
    const float* proj_b = (const float*)d_in[7];
    const float* c0w    = (const float*)d_in[8];
    const float* c0b    = (const float*)d_in[9];
    const float* c1w    = (const float*)d_in[10];
    const float* c1b    = (const float*)d_in[11];
    const float* n2g    = (const float*)d_in[12];
    const float* n2b    = (const float*)d_in[13];
    const float* fc1_w  = (const float*)d_in[14];
    const float* fc1_b  = (const float*)d_in[15];
    const float* fc2_w  = (const float*)d_in[16];
    const float* fc2_b  = (const float*)d_in[17];
    float* out = (float*)d_out;

    char* ws = (char*)d_ws;
    const size_t SZ_BF = (size_t)MROWS * C_DIM * 2;   // 12,845,056
    ushort* img  = (ushort*)(ws);
    ushort* att  = (ushort*)(ws + SZ_BF);
    ushort* big  = (ushort*)(ws + 2 * SZ_BF);               // qkv [M,768] / hidden [M,1024]
    char*   wbase = ws + 2 * SZ_BF + (size_t)MROWS * HID * 2;
    ushort* qkvT = (ushort*)(wbase);                        // [768][256]
    ushort* projT= (ushort*)(wbase +  393216);              // [256][256]
    ushort* fc1T = (ushort*)(wbase +  393216 + 131072);     // [1024][256]
    ushort* fc2T = (ushort*)(wbase +  393216 + 131072 + 524288); // [256][1024]

    // weights: transpose + cvt to bf16 (one fused launch)
    wcvt_all<<<192, 256, 0, stream>>>(qkv_w, proj_w, fc1_w, fc2_w, qkvT, projT, fc1T, fc2T);

    // 1. LN1 -> img (bf16)
    ln_kernel<<<MROWS / 4, 256, 0, stream>>>(x, n1g, n1b, img);
    // 2. qkv = img @ qkv_w  (bf16 out)
    gemm_bf16<0><<<dim3(768 / 128, MROWS / 128), 256, 0, stream>>>(
        img, qkvT, nullptr, nullptr, big, MROWS, 768, 256);
    // 3. attention + LePE -> att (bf16)
    attn_kernel<<<512, 512, 0, stream>>>(big, c0w, c0b, c1w, c1b, att);
    // 4. xr = x + att @ proj_w + proj_b -> d_out (f32)
    gemm_bf16<1><<<dim3(256 / 128, MROWS / 128), 256, 0, stream>>>(
        att, projT, proj_b, x, out, MROWS, 256, 256);
    // 5. LN2 -> img (bf16)
    ln_kernel<<<MROWS / 4, 256, 0, stream>>>(out, n2g, n2b, img);
    // 6. hidden = gelu(img @ fc1_w + fc1_b) (bf16)
    gemm_bf16<2><<<dim3(HID / 128, MROWS / 128), 256, 0, stream>>>(
        img, fc1T, fc1_b, nullptr, big, MROWS, HID, 256);
    // 7. out = xr + hidden @ fc2_w + fc2_b (f32, in-place residual)
    gemm_bf16<1><<<dim3(256 / 128, MROWS / 128), 256, 0, stream>>>(
        big, fc2T, fc2_b, out, out, MROWS, 256, 1024);
}

// Round 5
// 334.387 us; speedup vs baseline: 1.2858x; 1.2858x over previous
//
#include <hip/hip_runtime.h>
#include <hip/hip_bf16.h>
#include <math.h>

constexpr int C_DIM = 256;
constexpr int MROWS = 25088;   // B*H*W
constexpr int HID   = 1024;

typedef float  f32x4 __attribute__((ext_vector_type(4)));
typedef short  s16x8 __attribute__((ext_vector_type(8)));

__device__ __forceinline__ ushort f2bf(float f) {
    __hip_bfloat16 h = __float2bfloat16(f);
    return *reinterpret_cast<ushort*>(&h);
}
__device__ __forceinline__ unsigned pkbf2(float a, float b) {
    __hip_bfloat162 h = __float22bfloat162_rn(float2{a, b});
    return *reinterpret_cast<unsigned*>(&h);
}
__device__ __forceinline__ float bf2f(ushort u) {
    return __uint_as_float(((unsigned)u) << 16);
}

// async global->LDS, 16B per lane; dest = wave-uniform base + lane*16
typedef const __attribute__((address_space(1))) unsigned guint;
typedef __attribute__((address_space(3))) unsigned luint;
__device__ __forceinline__ void gload16(const void* g, void* l) {
    __builtin_amdgcn_global_load_lds((guint*)g, (luint*)l, 16, 0, 0);
}

// ---------------- LayerNorm: one wave per row, bf16 out ----------------
__global__ __launch_bounds__(256) void ln_kernel(
    const float* __restrict__ x, const float* __restrict__ g,
    const float* __restrict__ b, ushort* __restrict__ out)
{
    int wv = threadIdx.x >> 6, lane = threadIdx.x & 63;
    size_t row = (size_t)blockIdx.x * 4 + wv;
    float4 v = *(const float4*)(x + row * 256 + lane * 4);
    float s1 = v.x + v.y + v.z + v.w;
    float s2 = v.x*v.x + v.y*v.y + v.z*v.z + v.w*v.w;
    #pragma unroll
    for (int d = 1; d < 64; d <<= 1) {
        s1 += __shfl_xor(s1, d);
        s2 += __shfl_xor(s2, d);
    }
    float mu  = s1 * (1.0f / 256.0f);
    float var = s2 * (1.0f / 256.0f) - mu * mu;
    float inv = rsqrtf(var + 1e-5f);
    float4 gv = *(const float4*)(g + lane * 4);
    float4 bv = *(const float4*)(b + lane * 4);
    uint2 o;
    o.x = pkbf2((v.x - mu) * inv * gv.x + bv.x, (v.y - mu) * inv * gv.y + bv.y);
    o.y = pkbf2((v.z - mu) * inv * gv.z + bv.z, (v.w - mu) * inv * gv.w + bv.w);
    *(uint2*)(out + row * 256 + lane * 4) = o;
}

// ---------------- fused weight transpose + cvt: all four weights ----------------
__global__ __launch_bounds__(256) void wcvt_all(
    const float* __restrict__ w0, const float* __restrict__ w1,
    const float* __restrict__ w2, const float* __restrict__ w3,
    ushort* __restrict__ o0, ushort* __restrict__ o1,
    ushort* __restrict__ o2, ushort* __restrict__ o3)
{
    __shared__ ushort tile[64][65];
    int bid = blockIdx.x;
    const float* w; ushort* o; int K, N, tIdx;
    if (bid < 48)       { w = w0; o = o0; K = 256;  N = 768;  tIdx = bid; }
    else if (bid < 64)  { w = w1; o = o1; K = 256;  N = 256;  tIdx = bid - 48; }
    else if (bid < 128) { w = w2; o = o2; K = 256;  N = 1024; tIdx = bid - 64; }
    else                { w = w3; o = o3; K = 1024; N = 256;  tIdx = bid - 128; }
    int nx = N >> 6;
    int bx = tIdx % nx, by = tIdx / nx;
    int n0 = bx * 64, k0 = by * 64;
    int c = threadIdx.x & 63, rr = threadIdx.x >> 6;
    #pragma unroll
    for (int i = 0; i < 64; i += 4) {
        int r = i + rr;
        tile[r][c] = f2bf(w[(size_t)(k0 + r) * N + n0 + c]);
    }
    __syncthreads();
    #pragma unroll
    for (int i = 0; i < 64; i += 4) {
        int r = i + rr;
        o[(size_t)(n0 + r) * K + k0 + c] = tile[c][r];
    }
}

// ---------------- bf16 MFMA GEMM (m97 structure): C = A[M,K] @ Bt[N,K]^T ----------------
// FUSE: 0 = bf16 out; 1 = +bias +residual(f32), f32 out; 2 = +bias +GELU, bf16 out
template<int FUSE>
__global__ __launch_bounds__(256) void gemm_bf16(
    const ushort* __restrict__ A, const ushort* __restrict__ Bt,
    const float* __restrict__ bias, const float* res,
    void* Cout, int M, int N, int K)
{
    __shared__ ushort As[128 * 32];
    __shared__ ushort Bs[128 * 32];
    int tid  = threadIdx.x;
    int lane = tid & 63, wv = tid >> 6;
    int lr = lane & 15, lg = lane >> 4;
    int row0 = blockIdx.y * 128, col0 = blockIdx.x * 128;
    int wr = wv >> 1, wc = wv & 1;

    f32x4 acc[4][4];
    #pragma unroll
    for (int m = 0; m < 4; ++m)
        #pragma unroll
        for (int n = 0; n < 4; ++n)
            acc[m][n] = (f32x4){0.f, 0.f, 0.f, 0.f};

    int srow = wv * 32 + (lane >> 2);
    const ushort* gA  = A  + (size_t)(row0 + srow) * K + (lane & 3) * 8;
    const ushort* gA2 = gA + (size_t)16 * K;
    const ushort* gB  = Bt + (size_t)(col0 + srow) * K + (lane & 3) * 8;
    const ushort* gB2 = gB + (size_t)16 * K;
    ushort* lA  = &As[(wv * 32 +  0) * 32];
    ushort* lA2 = &As[(wv * 32 + 16) * 32];
    ushort* lB  = &Bs[(wv * 32 +  0) * 32];
    ushort* lB2 = &Bs[(wv * 32 + 16) * 32];

    for (int k0 = 0; k0 < K; k0 += 32) {
        gload16(gA  + k0, lA);
        gload16(gA2 + k0, lA2);
        gload16(gB  + k0, lB);
        gload16(gB2 + k0, lB2);
        __syncthreads();
        s16x8 af[4], bfg[4];
        #pragma unroll
        for (int m = 0; m < 4; ++m)
            af[m] = *(const s16x8*)&As[(wr * 64 + m * 16 + lr) * 32 + lg * 8];
        #pragma unroll
        for (int n = 0; n < 4; ++n)
            bfg[n] = *(const s16x8*)&Bs[(wc * 64 + n * 16 + lr) * 32 + lg * 8];
        #pragma unroll
        for (int m = 0; m < 4; ++m)
            #pragma unroll
            for (int n = 0; n < 4; ++n)
                acc[m][n] = __builtin_amdgcn_mfma_f32_16x16x32_bf16(af[m], bfg[n], acc[m][n], 0, 0, 0);
        __syncthreads();
    }

    int grow0 = row0 + wr * 64;
    int gcol0 = col0 + wc * 64;
    #pragma unroll
    for (int m = 0; m < 4; ++m) {
        #pragma unroll
        for (int n = 0; n < 4; ++n) {
            int gcol = gcol0 + n * 16 + lr;
            float bv = (FUSE >= 1) ? bias[gcol] : 0.0f;
            #pragma unroll
            for (int r = 0; r < 4; ++r) {
                int grow = grow0 + m * 16 + lg * 4 + r;
                float v = acc[m][n][r] + bv;
                if (FUSE == 2) v = 0.5f * v * (1.0f + erff(v * 0.70710678118654752f));
                if (FUSE == 1) {
                    v += res[(size_t)grow * N + gcol];
                    ((float*)Cout)[(size_t)grow * N + gcol] = v;
                } else {
                    ((ushort*)Cout)[(size_t)grow * N + gcol] = f2bf(v);
                }
            }
        }
    }
}

// ---------------- MFMA windowed attention + fused LePE (swapped-QK, no-max softmax) ----
// grid 512 = 2 branch x 64 win x 4 head; 512 threads = 8 waves.
// launch_bounds(512,2): min-waves 2/EU -> VGPR cap 256; (512,4) forced a 64+64
// VGPR/AGPR split and ~480 MB/dispatch of scratch spills (rounds 3-4 lesson).
__device__ __forceinline__ int wrow(int branch, int b, int wi, int n) {
    if (branch) return b * 3136 + wi * 392 + n;
    int ii = n / 7;
    return b * 3136 + ii * 56 + wi * 7 + (n - ii * 7);
}

__global__ __launch_bounds__(512, 2) void attn_kernel(
    const ushort* __restrict__ qkv,   // bf16 [M,768]
    const float* __restrict__ c0w, const float* __restrict__ c0b,
    const float* __restrict__ c1w, const float* __restrict__ c1b,
    ushort* __restrict__ att)         // bf16 [M,256]
{
    __shared__ ushort Kh[2 * 416 * 16];   // two d-half planes [416 k][16 d]  26,624 B
    __shared__ ushort Vt[32][424];        // V^T [d][k]                       27,136 B
    __shared__ ushort Pl[8][16][40];      // per-wave P chunk [16 q][32 k]    10,240 B
    __shared__ float  CwS[9][32];         // LePE conv weights for this (branch,head)
    __shared__ float  CbS[32];

    int bid    = blockIdx.x;
    int branch = bid >> 8;
    int rem    = bid & 255;
    int head   = rem & 3;
    int win    = rem >> 2;
    int b  = win >> 3, wi = win & 7;
    int c0 = branch * 128 + head * 32;
    const float* cw = branch ? c1w : c0w;
    const float* cb = branch ? c1b : c0b;
    int tid = threadIdx.x;

    // stage conv weights/bias
    if (tid < 288) {
        int tap = tid >> 5, d = tid & 31;
        CwS[tap][d] = cw[tap * 128 + head * 32 + d];
    } else if (tid < 320) {
        CbS[tid - 288] = cb[head * 32 + (tid - 288)];
    }
    // ---- stage K into two 16-wide planes (rows >=392 zero) ----
    for (int e = tid; e < 1664; e += 512) {
        int n = e >> 2, quad = e & 3;
        uint4 v = make_uint4(0u, 0u, 0u, 0u);
        if (n < 392) {
            int gr = wrow(branch, b, wi, n);
            v = *(const uint4*)(qkv + (size_t)gr * 768 + 256 + c0 + quad * 8);
        }
        *(uint4*)&Kh[(quad >> 1) * 6656 + n * 16 + (quad & 1) * 8] = v;
    }
    // ---- stage V transposed ----
    for (int e = tid; e < 1568; e += 512) {
        int n = e >> 2, quad = e & 3;
        int gr = wrow(branch, b, wi, n);
        uint4 v = *(const uint4*)(qkv + (size_t)gr * 768 + 512 + c0 + quad * 8);
        const ushort* us = (const ushort*)&v;
        #pragma unroll
        for (int j = 0; j < 8; ++j) Vt[quad * 8 + j][n] = us[j];
    }
    for (int e = tid; e < 1024; e += 512) {
        int d = e >> 5, k = 392 + (e & 31);
        Vt[d][k] = 0;
    }
    __syncthreads();

    int wv = tid >> 6, lane = tid & 63;
    int lr = lane & 15, lg = lane >> 4;
    constexpr float kSc = 0.17677669529663689f * 1.4426950408889634f;  // scale * log2(e)
    ushort* Pw = &Pl[wv][0][0];
    int Hsp = branch ? 7 : 56, Wsp = branch ? 56 : 7;
    const ushort* Kbase = &Kh[(lg >> 1) * 6656 + lr * 16 + (lg & 1) * 8];

    for (int qt = wv; qt < 25; qt += 8) {
        int q0 = qt * 16;
        int qn = q0 + lr; if (qn > 391) qn = 391;
        int qr = wrow(branch, b, wi, qn);
        s16x8 qf = *(const s16x8*)(qkv + (size_t)qr * 768 + c0 + lg * 8);

        f32x4 o0 = {0.f, 0.f, 0.f, 0.f}, o1 = {0.f, 0.f, 0.f, 0.f};
        float psum = 0.0f;

        auto do_chunk = [&](int c, bool last) {
            f32x4 z = {0.f, 0.f, 0.f, 0.f};
            s16x8 kf0 = *(const s16x8*)&Kbase[(c * 32)      * 16];
            s16x8 kf1 = *(const s16x8*)&Kbase[(c * 32 + 16) * 16];
            f32x4 s0 = __builtin_amdgcn_mfma_f32_16x16x32_bf16(kf0, qf, z, 0, 0, 0);
            f32x4 s1 = __builtin_amdgcn_mfma_f32_16x16x32_bf16(kf1, qf, z, 0, 0, 0);
            float p[2][4];
            #pragma unroll
            for (int r = 0; r < 4; ++r) {
                p[0][r] = exp2f(s0[r] * kSc);
                p[1][r] = exp2f(s1[r] * kSc);
            }
            if (last) {   // mask padding keys (k >= 392): chunk 12 covers 384..415
                #pragma unroll
                for (int t = 0; t < 2; ++t)
                    #pragma unroll
                    for (int r = 0; r < 4; ++r) {
                        int kk = 384 + t * 16 + lg * 4 + r;
                        if (kk >= 392) p[t][r] = 0.0f;
                    }
            }
            #pragma unroll
            for (int t = 0; t < 2; ++t)
                #pragma unroll
                for (int r = 0; r < 4; ++r) psum += p[t][r];
            uint2 w0, w1;
            w0.x = pkbf2(p[0][0], p[0][1]); w0.y = pkbf2(p[0][2], p[0][3]);
            w1.x = pkbf2(p[1][0], p[1][1]); w1.y = pkbf2(p[1][2], p[1][3]);
            *(uint2*)&Pw[lr * 40 + lg * 4]      = w0;
            *(uint2*)&Pw[lr * 40 + 16 + lg * 4] = w1;
            s16x8 pf = *(const s16x8*)&Pw[lr * 40 + lg * 8];
            s16x8 v0 = *(const s16x8*)&Vt[lr][c * 32 + lg * 8];
            s16x8 v1 = *(const s16x8*)&Vt[16 + lr][c * 32 + lg * 8];
            o0 = __builtin_amdgcn_mfma_f32_16x16x32_bf16(pf, v0, o0, 0, 0, 0);
            o1 = __builtin_amdgcn_mfma_f32_16x16x32_bf16(pf, v1, o1, 0, 0, 0);
        };

        for (int c = 0; c < 12; ++c) do_chunk(c, false);
        do_chunk(12, true);

        // finalize l per q (lane holds partial for q = lr): sum over the 4 lg groups
        psum += __shfl_xor(psum, 16);
        psum += __shfl_xor(psum, 32);
        // redistribute 1/l to output rows q = lg*4+r
        float linv[4];
        #pragma unroll
        for (int r = 0; r < 4; ++r)
            linv[r] = 1.0f / __shfl(psum, lg * 4 + r);
        #pragma unroll
        for (int r = 0; r < 4; ++r) { o0[r] *= linv[r]; o1[r] *= linv[r]; }

        // LePE conv + bias + store
        #pragma unroll
        for (int r = 0; r < 4; ++r) {
            int q = q0 + lg * 4 + r;
            if (q >= 392) continue;
            int ii = branch ? (q / 56) : (q / 7);
            int jj = q - ii * Wsp;
            float a0 = o0[r], a1 = o1[r];
            #pragma unroll
            for (int kh = 0; kh < 3; ++kh) {
                int i2 = ii + kh - 1;
                if ((unsigned)i2 >= (unsigned)Hsp) continue;
                #pragma unroll
                for (int kw = 0; kw < 3; ++kw) {
                    int j2 = jj + kw - 1;
                    if ((unsigned)j2 >= (unsigned)Wsp) continue;
                    int pos = i2 * Wsp + j2;
                    a0 += CwS[kh * 3 + kw][lr]      * bf2f(Vt[lr][pos]);
                    a1 += CwS[kh * 3 + kw][16 + lr] * bf2f(Vt[16 + lr][pos]);
                }
            }
            a0 += CbS[lr]; a1 += CbS[16 + lr];
            int gr = wrow(branch, b, wi, q);
            att[(size_t)gr * 256 + branch * 128 + head * 32 + lr]      = f2bf(a0);
            att[(size_t)gr * 256 + branch * 128 + head * 32 + 16 + lr] = f2bf(a1);
        }
    }
}

// ---------------- launcher ----------------
extern "C" void kernel_launch(void* const* d_in, const int* in_sizes, int n_in,
                              void* d_out, int out_size, void* d_ws, size_t ws_size,
                              hipStream_t stream)
{
    const float* x      = (const float*)d_in[0];
    const float* n1g    = (const float*)d_in[3];
    const float* n1b    = (const float*)d_in[4];
    const float* qkv_w  = (const float*)d_in[5];
    const float* proj_w = (const float*)d_in[6];
    const float* proj_b = (const float*)d_in[7];
    const float* c0w    = (const float*)d_in[8];
    const float* c0b    = (const float*)d_in[9];
    const float* c1w    = (const float*)d_in[10];
    const float* c1b    = (const float*)d_in[11];
    const float* n2g    = (const float*)d_in[12];
    const float* n2b    = (const float*)d_in[13];
    const float* fc1_w  = (const float*)d_in[14];
    const float* fc1_b  = (const float*)d_in[15];
    const float* fc2_w  = (const float*)d_in[16];
    const float* fc2_b  = (const float*)d_in[17];
    float* out = (float*)d_out;

    char* ws = (char*)d_ws;
    const size_t SZ_BF = (size_t)MROWS * C_DIM * 2;   // 12,845,056
    ushort* img  = (ushort*)(ws);
    ushort* att  = (ushort*)(ws + SZ_BF);
    ushort* big  = (ushort*)(ws + 2 * SZ_BF);               // qkv [M,768] / hidden [M,1024]
    char*   wbase = ws + 2 * SZ_BF + (size_t)MROWS * HID * 2;
    ushort* qkvT = (ushort*)(wbase);                        // [768][256]
    ushort* projT= (ushort*)(wbase +  393216);              // [256][256]
    ushort* fc1T = (ushort*)(wbase +  393216 + 131072);     // [1024][256]
    ushort* fc2T = (ushort*)(wbase +  393216 + 131072 + 524288); // [256][1024]

    // weights: transpose + cvt to bf16 (one fused launch)
    wcvt_all<<<192, 256, 0, stream>>>(qkv_w, proj_w, fc1_w, fc2_w, qkvT, projT, fc1T, fc2T);

    // 1. LN1 -> img (bf16)
    ln_kernel<<<MROWS / 4, 256, 0, stream>>>(x, n1g, n1b, img);
    // 2. qkv = img @ qkv_w  (bf16 out)
    gemm_bf16<0><<<dim3(768 / 128, MROWS / 128), 256, 0, stream>>>(
        img, qkvT, nullptr, nullptr, big, MROWS, 768, 256);
    // 3. attention + LePE -> att (bf16)
    attn_kernel<<<512, 512, 0, stream>>>(big, c0w, c0b, c1w, c1b, att);
    // 4. xr = x + att @ proj_w + proj_b -> d_out (f32)
    gemm_bf16<1><<<dim3(256 / 128, MROWS / 128), 256, 0, stream>>>(
        att, projT, proj_b, x, out, MROWS, 256, 256);
    // 5. LN2 -> img (bf16)
    ln_kernel<<<MROWS / 4, 256, 0, stream>>>(out, n2g, n2b, img);
    // 6. hidden = gelu(img @ fc1_w + fc1_b) (bf16)
    gemm_bf16<2><<<dim3(HID / 128, MROWS / 128), 256, 0, stream>>>(
        img, fc1T, fc1_b, nullptr, big, MROWS, HID, 256);
    // 7. out = xr + hidden @ fc2_w + fc2_b (f32, in-place residual)
    gemm_bf16<1><<<dim3(256 / 128, MROWS / 128), 256, 0, stream>>>(
        big, fc2T, fc2_b, out, out, MROWS, 256, 1024);
}

// Round 6
// 312.591 us; speedup vs baseline: 1.3755x; 1.0697x over previous
//
#include <hip/hip_runtime.h>
#include <hip/hip_bf16.h>
#include <math.h>

constexpr int C_DIM = 256;
constexpr int MROWS = 25088;   // B*H*W
constexpr int HID   = 1024;

typedef float  f32x4 __attribute__((ext_vector_type(4)));
typedef short  s16x8 __attribute__((ext_vector_type(8)));

__device__ __forceinline__ ushort f2bf(float f) {
    __hip_bfloat16 h = __float2bfloat16(f);
    return *reinterpret_cast<ushort*>(&h);
}
__device__ __forceinline__ unsigned pkbf2(float a, float b) {
    __hip_bfloat162 h = __float22bfloat162_rn(float2{a, b});
    return *reinterpret_cast<unsigned*>(&h);
}
__device__ __forceinline__ float bf2f(ushort u) {
    return __uint_as_float(((unsigned)u) << 16);
}

// tanh-form GELU; |err vs exact erf-GELU| < 4e-4 (bf16 output swallows it)
__device__ __forceinline__ float fast_gelu(float v) {
    float u = v * (0.7978845608028654f + 0.035677408136f * v * v);
    float e = __expf(2.0f * u);
    float t = 1.0f - 2.0f / (e + 1.0f);   // tanh(u); saturates correctly at +/-inf
    return 0.5f * v * (1.0f + t);
}

// async global->LDS, 16B per lane; dest = wave-uniform base + lane*16
typedef const __attribute__((address_space(1))) unsigned guint;
typedef __attribute__((address_space(3))) unsigned luint;
__device__ __forceinline__ void gload16(const void* g, void* l) {
    __builtin_amdgcn_global_load_lds((guint*)g, (luint*)l, 16, 0, 0);
}

// ---------------- LayerNorm: one wave per row, bf16 out ----------------
__global__ __launch_bounds__(256) void ln_kernel(
    const float* __restrict__ x, const float* __restrict__ g,
    const float* __restrict__ b, ushort* __restrict__ out)
{
    int wv = threadIdx.x >> 6, lane = threadIdx.x & 63;
    size_t row = (size_t)blockIdx.x * 4 + wv;
    float4 v = *(const float4*)(x + row * 256 + lane * 4);
    float s1 = v.x + v.y + v.z + v.w;
    float s2 = v.x*v.x + v.y*v.y + v.z*v.z + v.w*v.w;
    #pragma unroll
    for (int d = 1; d < 64; d <<= 1) {
        s1 += __shfl_xor(s1, d);
        s2 += __shfl_xor(s2, d);
    }
    float mu  = s1 * (1.0f / 256.0f);
    float var = s2 * (1.0f / 256.0f) - mu * mu;
    float inv = rsqrtf(var + 1e-5f);
    float4 gv = *(const float4*)(g + lane * 4);
    float4 bv = *(const float4*)(b + lane * 4);
    uint2 o;
    o.x = pkbf2((v.x - mu) * inv * gv.x + bv.x, (v.y - mu) * inv * gv.y + bv.y);
    o.y = pkbf2((v.z - mu) * inv * gv.z + bv.z, (v.w - mu) * inv * gv.w + bv.w);
    *(uint2*)(out + row * 256 + lane * 4) = o;
}

// ---------------- fused weight transpose + cvt: all four weights ----------------
__global__ __launch_bounds__(256) void wcvt_all(
    const float* __restrict__ w0, const float* __restrict__ w1,
    const float* __restrict__ w2, const float* __restrict__ w3,
    ushort* __restrict__ o0, ushort* __restrict__ o1,
    ushort* __restrict__ o2, ushort* __restrict__ o3)
{
    __shared__ ushort tile[64][65];
    int bid = blockIdx.x;
    const float* w; ushort* o; int K, N, tIdx;
    if (bid < 48)       { w = w0; o = o0; K = 256;  N = 768;  tIdx = bid; }
    else if (bid < 64)  { w = w1; o = o1; K = 256;  N = 256;  tIdx = bid - 48; }
    else if (bid < 128) { w = w2; o = o2; K = 256;  N = 1024; tIdx = bid - 64; }
    else                { w = w3; o = o3; K = 1024; N = 256;  tIdx = bid - 128; }
    int nx = N >> 6;
    int bx = tIdx % nx, by = tIdx / nx;
    int n0 = bx * 64, k0 = by * 64;
    int c = threadIdx.x & 63, rr = threadIdx.x >> 6;
    #pragma unroll
    for (int i = 0; i < 64; i += 4) {
        int r = i + rr;
        tile[r][c] = f2bf(w[(size_t)(k0 + r) * N + n0 + c]);
    }
    __syncthreads();
    #pragma unroll
    for (int i = 0; i < 64; i += 4) {
        int r = i + rr;
        o[(size_t)(n0 + r) * K + k0 + c] = tile[c][r];
    }
}

// ---------------- bf16 MFMA GEMM: C = A[M,K] @ Bt[N,K]^T ----------------
// 2-phase double-buffered staging (T3-min); transposed-C fragments via swapped
// MFMA operands -> vectorized epilogue; m204 bijective XCD swizzle on 1D grid.
// FUSE: 0 = bf16 out; 1 = +bias +residual(f32), f32 out; 2 = +bias +GELU, bf16 out
template<int FUSE>
__global__ __launch_bounds__(256) void gemm_bf16(
    const ushort* __restrict__ A, const ushort* __restrict__ Bt,
    const float* __restrict__ bias, const float* res,
    void* Cout, int M, int N, int K, int NBX)
{
    __shared__ ushort As[2][128 * 32];
    __shared__ ushort Bs[2][128 * 32];
    int tid  = threadIdx.x;
    int lane = tid & 63, wv = tid >> 6;
    int lr = lane & 15, lg = lane >> 4;

    // bijective XCD swizzle (m204): hardware round-robins blockIdx across 8 XCDs;
    // remap so each XCD owns a contiguous chunk of output tiles (B-panel L2 reuse).
    int nwg = gridDim.x;
    int qc = nwg >> 3, rc = nwg & 7;
    int xcd = blockIdx.x & 7, pos = blockIdx.x >> 3;
    int wg = (xcd < rc ? xcd * (qc + 1) : rc * (qc + 1) + (xcd - rc) * qc) + pos;
    int row0 = (wg / NBX) * 128, col0 = (wg % NBX) * 128;
    int wr = wv >> 1, wc = wv & 1;

    f32x4 acc[4][4];   // [n][m] — transposed-C fragment order
    #pragma unroll
    for (int n = 0; n < 4; ++n)
        #pragma unroll
        for (int m = 0; m < 4; ++m)
            acc[n][m] = (f32x4){0.f, 0.f, 0.f, 0.f};

    int srow = wv * 32 + (lane >> 2);
    const ushort* gA  = A  + (size_t)(row0 + srow) * K + (lane & 3) * 8;
    const ushort* gA2 = gA + (size_t)16 * K;
    const ushort* gB  = Bt + (size_t)(col0 + srow) * K + (lane & 3) * 8;
    const ushort* gB2 = gB + (size_t)16 * K;

#define STAGE(buf, k0) do {                                      \
        gload16(gA  + (k0), &As[buf][(wv * 32 +  0) * 32]);      \
        gload16(gA2 + (k0), &As[buf][(wv * 32 + 16) * 32]);      \
        gload16(gB  + (k0), &Bs[buf][(wv * 32 +  0) * 32]);      \
        gload16(gB2 + (k0), &Bs[buf][(wv * 32 + 16) * 32]);      \
    } while (0)

#define COMPUTE(buf) do {                                                          \
        s16x8 af[4], bfg[4];                                                       \
        _Pragma("unroll")                                                          \
        for (int m = 0; m < 4; ++m)                                                \
            af[m] = *(const s16x8*)&As[buf][(wr * 64 + m * 16 + lr) * 32 + lg * 8];\
        _Pragma("unroll")                                                          \
        for (int n = 0; n < 4; ++n)                                                \
            bfg[n] = *(const s16x8*)&Bs[buf][(wc * 64 + n * 16 + lr) * 32 + lg * 8];\
        _Pragma("unroll")                                                          \
        for (int n = 0; n < 4; ++n)                                                \
            _Pragma("unroll")                                                      \
            for (int m = 0; m < 4; ++m)                                            \
                acc[n][m] = __builtin_amdgcn_mfma_f32_16x16x32_bf16(               \
                    bfg[n], af[m], acc[n][m], 0, 0, 0);                            \
    } while (0)

    STAGE(0, 0);
    __syncthreads();
    #pragma unroll 1
    for (int k0 = 0; k0 + 64 <= K; k0 += 64) {
        STAGE(1, k0 + 32);
        COMPUTE(0);
        __syncthreads();
        if (k0 + 64 < K) STAGE(0, k0 + 64);
        COMPUTE(1);
        __syncthreads();
    }
#undef STAGE
#undef COMPUTE

    // Transposed-C epilogue: lane holds rows grow0+m*16+lr, 4 consecutive cols
    // gcol0+n*16+lg*4+r -> 8B/16B vector stores.
    int grow0 = row0 + wr * 64;
    int gcol0 = col0 + wc * 64;
    #pragma unroll
    for (int n = 0; n < 4; ++n) {
        int gcol = gcol0 + n * 16 + lg * 4;
        float4 b4 = make_float4(0.f, 0.f, 0.f, 0.f);
        if (FUSE >= 1) b4 = *(const float4*)&bias[gcol];
        #pragma unroll
        for (int m = 0; m < 4; ++m) {
            int grow = grow0 + m * 16 + lr;
            float v0 = acc[n][m][0] + b4.x;
            float v1 = acc[n][m][1] + b4.y;
            float v2 = acc[n][m][2] + b4.z;
            float v3 = acc[n][m][3] + b4.w;
            if (FUSE == 2) {
                v0 = fast_gelu(v0); v1 = fast_gelu(v1);
                v2 = fast_gelu(v2); v3 = fast_gelu(v3);
            }
            if (FUSE == 1) {
                const float4 rr = *(const float4*)&res[(size_t)grow * N + gcol];
                float4 o = make_float4(v0 + rr.x, v1 + rr.y, v2 + rr.z, v3 + rr.w);
                *(float4*)&((float*)Cout)[(size_t)grow * N + gcol] = o;
            } else {
                uint2 o;
                o.x = pkbf2(v0, v1);
                o.y = pkbf2(v2, v3);
                *(uint2*)&((ushort*)Cout)[(size_t)grow * N + gcol] = o;
            }
        }
    }
}

// ---------------- MFMA windowed attention + fused LePE (swapped-QK, no-max softmax) ----
// grid 512 = 2 branch x 64 win x 4 head; 512 threads = 8 waves.  UNCHANGED from round 5.
__device__ __forceinline__ int wrow(int branch, int b, int wi, int n) {
    if (branch) return b * 3136 + wi * 392 + n;
    int ii = n / 7;
    return b * 3136 + ii * 56 + wi * 7 + (n - ii * 7);
}

__global__ __launch_bounds__(512, 2) void attn_kernel(
    const ushort* __restrict__ qkv,   // bf16 [M,768]
    const float* __restrict__ c0w, const float* __restrict__ c0b,
    const float* __restrict__ c1w, const float* __restrict__ c1b,
    ushort* __restrict__ att)         // bf16 [M,256]
{
    __shared__ ushort Kh[2 * 416 * 16];   // two d-half planes [416 k][16 d]  26,624 B
    __shared__ ushort Vt[32][424];        // V^T [d][k]                       27,136 B
    __shared__ ushort Pl[8][16][40];      // per-wave P chunk [16 q][32 k]    10,240 B
    __shared__ float  CwS[9][32];         // LePE conv weights for this (branch,head)
    __shared__ float  CbS[32];

    int bid    = blockIdx.x;
    int branch = bid >> 8;
    int rem    = bid & 255;
    int head   = rem & 3;
    int win    = rem >> 2;
    int b  = win >> 3, wi = win & 7;
    int c0 = branch * 128 + head * 32;
    const float* cw = branch ? c1w : c0w;
    const float* cb = branch ? c1b : c0b;
    int tid = threadIdx.x;

    // stage conv weights/bias
    if (tid < 288) {
        int tap = tid >> 5, d = tid & 31;
        CwS[tap][d] = cw[tap * 128 + head * 32 + d];
    } else if (tid < 320) {
        CbS[tid - 288] = cb[head * 32 + (tid - 288)];
    }
    // ---- stage K into two 16-wide planes (rows >=392 zero) ----
    for (int e = tid; e < 1664; e += 512) {
        int n = e >> 2, quad = e & 3;
        uint4 v = make_uint4(0u, 0u, 0u, 0u);
        if (n < 392) {
            int gr = wrow(branch, b, wi, n);
            v = *(const uint4*)(qkv + (size_t)gr * 768 + 256 + c0 + quad * 8);
        }
        *(uint4*)&Kh[(quad >> 1) * 6656 + n * 16 + (quad & 1) * 8] = v;
    }
    // ---- stage V transposed ----
    for (int e = tid; e < 1568; e += 512) {
        int n = e >> 2, quad = e & 3;
        int gr = wrow(branch, b, wi, n);
        uint4 v = *(const uint4*)(qkv + (size_t)gr * 768 + 512 + c0 + quad * 8);
        const ushort* us = (const ushort*)&v;
        #pragma unroll
        for (int j = 0; j < 8; ++j) Vt[quad * 8 + j][n] = us[j];
    }
    for (int e = tid; e < 1024; e += 512) {
        int d = e >> 5, k = 392 + (e & 31);
        Vt[d][k] = 0;
    }
    __syncthreads();

    int wv = tid >> 6, lane = tid & 63;
    int lr = lane & 15, lg = lane >> 4;
    constexpr float kSc = 0.17677669529663689f * 1.4426950408889634f;  // scale * log2(e)
    ushort* Pw = &Pl[wv][0][0];
    int Hsp = branch ? 7 : 56, Wsp = branch ? 56 : 7;
    const ushort* Kbase = &Kh[(lg >> 1) * 6656 + lr * 16 + (lg & 1) * 8];

    for (int qt = wv; qt < 25; qt += 8) {
        int q0 = qt * 16;
        int qn = q0 + lr; if (qn > 391) qn = 391;
        int qr = wrow(branch, b, wi, qn);
        s16x8 qf = *(const s16x8*)(qkv + (size_t)qr * 768 + c0 + lg * 8);

        f32x4 o0 = {0.f, 0.f, 0.f, 0.f}, o1 = {0.f, 0.f, 0.f, 0.f};
        float psum = 0.0f;

        auto do_chunk = [&](int c, bool last) {
            f32x4 z = {0.f, 0.f, 0.f, 0.f};
            s16x8 kf0 = *(const s16x8*)&Kbase[(c * 32)      * 16];
            s16x8 kf1 = *(const s16x8*)&Kbase[(c * 32 + 16) * 16];
            f32x4 s0 = __builtin_amdgcn_mfma_f32_16x16x32_bf16(kf0, qf, z, 0, 0, 0);
            f32x4 s1 = __builtin_amdgcn_mfma_f32_16x16x32_bf16(kf1, qf, z, 0, 0, 0);
            float p[2][4];
            #pragma unroll
            for (int r = 0; r < 4; ++r) {
                p[0][r] = exp2f(s0[r] * kSc);
                p[1][r] = exp2f(s1[r] * kSc);
            }
            if (last) {   // mask padding keys (k >= 392): chunk 12 covers 384..415
                #pragma unroll
                for (int t = 0; t < 2; ++t)
                    #pragma unroll
                    for (int r = 0; r < 4; ++r) {
                        int kk = 384 + t * 16 + lg * 4 + r;
                        if (kk >= 392) p[t][r] = 0.0f;
                    }
            }
            #pragma unroll
            for (int t = 0; t < 2; ++t)
                #pragma unroll
                for (int r = 0; r < 4; ++r) psum += p[t][r];
            uint2 w0, w1;
            w0.x = pkbf2(p[0][0], p[0][1]); w0.y = pkbf2(p[0][2], p[0][3]);
            w1.x = pkbf2(p[1][0], p[1][1]); w1.y = pkbf2(p[1][2], p[1][3]);
            *(uint2*)&Pw[lr * 40 + lg * 4]      = w0;
            *(uint2*)&Pw[lr * 40 + 16 + lg * 4] = w1;
            s16x8 pf = *(const s16x8*)&Pw[lr * 40 + lg * 8];
            s16x8 v0 = *(const s16x8*)&Vt[lr][c * 32 + lg * 8];
            s16x8 v1 = *(const s16x8*)&Vt[16 + lr][c * 32 + lg * 8];
            o0 = __builtin_amdgcn_mfma_f32_16x16x32_bf16(pf, v0, o0, 0, 0, 0);
            o1 = __builtin_amdgcn_mfma_f32_16x16x32_bf16(pf, v1, o1, 0, 0, 0);
        };

        for (int c = 0; c < 12; ++c) do_chunk(c, false);
        do_chunk(12, true);

        // finalize l per q (lane holds partial for q = lr): sum over the 4 lg groups
        psum += __shfl_xor(psum, 16);
        psum += __shfl_xor(psum, 32);
        // redistribute 1/l to output rows q = lg*4+r
        float linv[4];
        #pragma unroll
        for (int r = 0; r < 4; ++r)
            linv[r] = 1.0f / __shfl(psum, lg * 4 + r);
        #pragma unroll
        for (int r = 0; r < 4; ++r) { o0[r] *= linv[r]; o1[r] *= linv[r]; }

        // LePE conv + bias + store
        #pragma unroll
        for (int r = 0; r < 4; ++r) {
            int q = q0 + lg * 4 + r;
            if (q >= 392) continue;
            int ii = branch ? (q / 56) : (q / 7);
            int jj = q - ii * Wsp;
            float a0 = o0[r], a1 = o1[r];
            #pragma unroll
            for (int kh = 0; kh < 3; ++kh) {
                int i2 = ii + kh - 1;
                if ((unsigned)i2 >= (unsigned)Hsp) continue;
                #pragma unroll
                for (int kw = 0; kw < 3; ++kw) {
                    int j2 = jj + kw - 1;
                    if ((unsigned)j2 >= (unsigned)Wsp) continue;
                    int pos = i2 * Wsp + j2;
                    a0 += CwS[kh * 3 + kw][lr]      * bf2f(Vt[lr][pos]);
                    a1 += CwS[kh * 3 + kw][16 + lr] * bf2f(Vt[16 + lr][pos]);
                }
            }
            a0 += CbS[lr]; a1 += CbS[16 + lr];
            int gr = wrow(branch, b, wi, q);
            att[(size_t)gr * 256 + branch * 128 + head * 32 + lr]      = f2bf(a0);
            att[(size_t)gr * 256 + branch * 128 + head * 32 + 16 + lr] = f2bf(a1);
        }
    }
}

// ---------------- launcher ----------------
extern "C" void kernel_launch(void* const* d_in, const int* in_sizes, int n_in,
                              void* d_out, int out_size, void* d_ws, size_t ws_size,
                              hipStream_t stream)
{
    const float* x      = (const float*)d_in[0];
    const float* n1g    = (const float*)d_in[3];
    const float* n1b    = (const float*)d_in[4];
    const float* qkv_w  = (const float*)d_in[5];
    const float* proj_w = (const float*)d_in[6];
    const float* proj_b = (const float*)d_in[7];
    const float* c0w    = (const float*)d_in[8];
    const float* c0b    = (const float*)d_in[9];
    const float* c1w    = (const float*)d_in[10];
    const float* c1b    = (const float*)d_in[11];
    const float* n2g    = (const float*)d_in[12];
    const float* n2b    = (const float*)d_in[13];
    const float* fc1_w  = (const float*)d_in[14];
    const float* fc1_b  = (const float*)d_in[15];
    const float* fc2_w  = (const float*)d_in[16];
    const float* fc2_b  = (const float*)d_in[17];
    float* out = (float*)d_out;

    char* ws = (char*)d_ws;
    const size_t SZ_BF = (size_t)MROWS * C_DIM * 2;   // 12,845,056
    ushort* img  = (ushort*)(ws);
    ushort* att  = (ushort*)(ws + SZ_BF);
    ushort* big  = (ushort*)(ws + 2 * SZ_BF);               // qkv [M,768] / hidden [M,1024]
    char*   wbase = ws + 2 * SZ_BF + (size_t)MROWS * HID * 2;
    ushort* qkvT = (ushort*)(wbase);                        // [768][256]
    ushort* projT= (ushort*)(wbase +  393216);              // [256][256]
    ushort* fc1T = (ushort*)(wbase +  393216 + 131072);     // [1024][256]
    ushort* fc2T = (ushort*)(wbase +  393216 + 131072 + 524288); // [256][1024]

    // weights: transpose + cvt to bf16 (one fused launch)
    wcvt_all<<<192, 256, 0, stream>>>(qkv_w, proj_w, fc1_w, fc2_w, qkvT, projT, fc1T, fc2T);

    // 1. LN1 -> img (bf16)
    ln_kernel<<<MROWS / 4, 256, 0, stream>>>(x, n1g, n1b, img);
    // 2. qkv = img @ qkv_w  (bf16 out)   grid 196*6
    gemm_bf16<0><<<196 * 6, 256, 0, stream>>>(
        img, qkvT, nullptr, nullptr, big, MROWS, 768, 256, 6);
    // 3. attention + LePE -> att (bf16)
    attn_kernel<<<512, 512, 0, stream>>>(big, c0w, c0b, c1w, c1b, att);
    // 4. xr = x + att @ proj_w + proj_b -> d_out (f32)   grid 196*2
    gemm_bf16<1><<<196 * 2, 256, 0, stream>>>(
        att, projT, proj_b, x, out, MROWS, 256, 256, 2);
    // 5. LN2 -> img (bf16)
    ln_kernel<<<MROWS / 4, 256, 0, stream>>>(out, n2g, n2b, img);
    // 6. hidden = gelu(img @ fc1_w + fc1_b) (bf16)   grid 196*8
    gemm_bf16<2><<<196 * 8, 256, 0, stream>>>(
        img, fc1T, fc1_b, nullptr, big, MROWS, HID, 256, 8);
    // 7. out = xr + hidden @ fc2_w + fc2_b (f32, in-place residual)   grid 196*2
    gemm_bf16<1><<<196 * 2, 256, 0, stream>>>(
        big, fc2T, fc2_b, out, out, MROWS, 256, 1024, 2);
}

// Round 7
// 273.999 us; speedup vs baseline: 1.5692x; 1.1408x over previous
//
#include <hip/hip_runtime.h>
#include <hip/hip_bf16.h>
#include <math.h>

constexpr int C_DIM = 256;
constexpr int MROWS = 25088;   // B*H*W
constexpr int HID   = 1024;

typedef float  f32x4 __attribute__((ext_vector_type(4)));
typedef short  s16x8 __attribute__((ext_vector_type(8)));

__device__ __forceinline__ ushort f2bf(float f) {
    __hip_bfloat16 h = __float2bfloat16(f);
    return *reinterpret_cast<ushort*>(&h);
}
__device__ __forceinline__ unsigned pkbf2(float a, float b) {
    __hip_bfloat162 h = __float22bfloat162_rn(float2{a, b});
    return *reinterpret_cast<unsigned*>(&h);
}
__device__ __forceinline__ float bf2f(ushort u) {
    return __uint_as_float(((unsigned)u) << 16);
}

// tanh-form GELU; |err vs exact erf-GELU| < 4e-4 (bf16 output swallows it)
__device__ __forceinline__ float fast_gelu(float v) {
    float u = v * (0.7978845608028654f + 0.035677408136f * v * v);
    float e = __expf(2.0f * u);
    float t = 1.0f - 2.0f / (e + 1.0f);
    return 0.5f * v * (1.0f + t);
}

// async global->LDS, 16B per lane; dest = wave-uniform base + lane*16
typedef const __attribute__((address_space(1))) unsigned guint;
typedef __attribute__((address_space(3))) unsigned luint;
__device__ __forceinline__ void gload16(const void* g, void* l) {
    __builtin_amdgcn_global_load_lds((guint*)g, (luint*)l, 16, 0, 0);
}

// ---------------- LayerNorm: one wave per row, bf16 out ----------------
__global__ __launch_bounds__(256) void ln_kernel(
    const float* __restrict__ x, const float* __restrict__ g,
    const float* __restrict__ b, ushort* __restrict__ out)
{
    int wv = threadIdx.x >> 6, lane = threadIdx.x & 63;
    size_t row = (size_t)blockIdx.x * 4 + wv;
    float4 v = *(const float4*)(x + row * 256 + lane * 4);
    float s1 = v.x + v.y + v.z + v.w;
    float s2 = v.x*v.x + v.y*v.y + v.z*v.z + v.w*v.w;
    #pragma unroll
    for (int d = 1; d < 64; d <<= 1) {
        s1 += __shfl_xor(s1, d);
        s2 += __shfl_xor(s2, d);
    }
    float mu  = s1 * (1.0f / 256.0f);
    float var = s2 * (1.0f / 256.0f) - mu * mu;
    float inv = rsqrtf(var + 1e-5f);
    float4 gv = *(const float4*)(g + lane * 4);
    float4 bv = *(const float4*)(b + lane * 4);
    uint2 o;
    o.x = pkbf2((v.x - mu) * inv * gv.x + bv.x, (v.y - mu) * inv * gv.y + bv.y);
    o.y = pkbf2((v.z - mu) * inv * gv.z + bv.z, (v.w - mu) * inv * gv.w + bv.w);
    *(uint2*)(out + row * 256 + lane * 4) = o;
}

// ---------------- fused weight transpose + cvt: all four weights ----------------
__global__ __launch_bounds__(256) void wcvt_all(
    const float* __restrict__ w0, const float* __restrict__ w1,
    const float* __restrict__ w2, const float* __restrict__ w3,
    ushort* __restrict__ o0, ushort* __restrict__ o1,
    ushort* __restrict__ o2, ushort* __restrict__ o3)
{
    __shared__ ushort tile[64][65];
    int bid = blockIdx.x;
    const float* w; ushort* o; int K, N, tIdx;
    if (bid < 48)       { w = w0; o = o0; K = 256;  N = 768;  tIdx = bid; }
    else if (bid < 64)  { w = w1; o = o1; K = 256;  N = 256;  tIdx = bid - 48; }
    else if (bid < 128) { w = w2; o = o2; K = 256;  N = 1024; tIdx = bid - 64; }
    else                { w = w3; o = o3; K = 1024; N = 256;  tIdx = bid - 128; }
    int nx = N >> 6;
    int bx = tIdx % nx, by = tIdx / nx;
    int n0 = bx * 64, k0 = by * 64;
    int c = threadIdx.x & 63, rr = threadIdx.x >> 6;
    #pragma unroll
    for (int i = 0; i < 64; i += 4) {
        int r = i + rr;
        tile[r][c] = f2bf(w[(size_t)(k0 + r) * N + n0 + c]);
    }
    __syncthreads();
    #pragma unroll
    for (int i = 0; i < 64; i += 4) {
        int r = i + rr;
        o[(size_t)(n0 + r) * K + k0 + c] = tile[c][r];
    }
}

// ---------------- bf16 MFMA GEMM: C = A[M,K] @ Bt[N,K]^T ----------------
// 3-buffer depth-2 pipeline with COUNTED vmcnt (T4): newest stage stays in
// flight across the barrier; only the next-needed tile is drained.
// FUSE: 0 = bf16 out; 1 = +bias +residual(f32), f32 out; 2 = +bias +GELU, bf16 out
template<int FUSE>
__global__ __launch_bounds__(256) void gemm_bf16(
    const ushort* __restrict__ A, const ushort* __restrict__ Bt,
    const float* __restrict__ bias, const float* res,
    void* Cout, int M, int N, int K, int NBX)
{
    __shared__ __align__(16) ushort As[3][128 * 32];
    __shared__ __align__(16) ushort Bs[3][128 * 32];
    int tid  = threadIdx.x;
    int lane = tid & 63, wv = tid >> 6;
    int lr = lane & 15, lg = lane >> 4;

    // bijective XCD swizzle (m204)
    int nwg = gridDim.x;
    int qc = nwg >> 3, rc = nwg & 7;
    int xcd = blockIdx.x & 7, pos = blockIdx.x >> 3;
    int wg = (xcd < rc ? xcd * (qc + 1) : rc * (qc + 1) + (xcd - rc) * qc) + pos;
    int row0 = (wg / NBX) * 128, col0 = (wg % NBX) * 128;
    int wr = wv >> 1, wc = wv & 1;

    f32x4 acc[4][4];   // [n][m] transposed-C fragment order
    #pragma unroll
    for (int n = 0; n < 4; ++n)
        #pragma unroll
        for (int m = 0; m < 4; ++m)
            acc[n][m] = (f32x4){0.f, 0.f, 0.f, 0.f};

    int srow = wv * 32 + (lane >> 2);
    const ushort* gA  = A  + (size_t)(row0 + srow) * K + (lane & 3) * 8;
    const ushort* gA2 = gA + (size_t)16 * K;
    const ushort* gB  = Bt + (size_t)(col0 + srow) * K + (lane & 3) * 8;
    const ushort* gB2 = gB + (size_t)16 * K;

    auto stage = [&](int buf, int k0) {
        gload16(gA  + k0, &As[buf][(wv * 32 +  0) * 32]);
        gload16(gA2 + k0, &As[buf][(wv * 32 + 16) * 32]);
        gload16(gB  + k0, &Bs[buf][(wv * 32 +  0) * 32]);
        gload16(gB2 + k0, &Bs[buf][(wv * 32 + 16) * 32]);
    };

    const int NSTEP = K >> 5;
    stage(0, 0);
    stage(1, 32);
    asm volatile("s_waitcnt vmcnt(4)\n\ts_barrier" ::: "memory");

    for (int i = 0; i < NSTEP; ++i) {
        int cur = i % 3;
        const ushort* as = As[cur];
        const ushort* bs = Bs[cur];
        s16x8 af[4], bfg[4];
        #pragma unroll
        for (int m = 0; m < 4; ++m)
            af[m] = *(const s16x8*)&as[(wr * 64 + m * 16 + lr) * 32 + lg * 8];
        #pragma unroll
        for (int n = 0; n < 4; ++n)
            bfg[n] = *(const s16x8*)&bs[(wc * 64 + n * 16 + lr) * 32 + lg * 8];
        if (i + 2 < NSTEP) stage((i + 2) % 3, (i + 2) * 32);
        #pragma unroll
        for (int n = 0; n < 4; ++n)
            #pragma unroll
            for (int m = 0; m < 4; ++m)
                acc[n][m] = __builtin_amdgcn_mfma_f32_16x16x32_bf16(
                    bfg[n], af[m], acc[n][m], 0, 0, 0);
        if (i + 2 < NSTEP)
            asm volatile("s_waitcnt vmcnt(4)\n\ts_barrier" ::: "memory");
        else if (i + 1 < NSTEP)
            asm volatile("s_waitcnt vmcnt(0)\n\ts_barrier" ::: "memory");
    }

    // Transposed-C epilogue: vectorized stores
    int grow0 = row0 + wr * 64;
    int gcol0 = col0 + wc * 64;
    #pragma unroll
    for (int n = 0; n < 4; ++n) {
        int gcol = gcol0 + n * 16 + lg * 4;
        float4 b4 = make_float4(0.f, 0.f, 0.f, 0.f);
        if (FUSE >= 1) b4 = *(const float4*)&bias[gcol];
        #pragma unroll
        for (int m = 0; m < 4; ++m) {
            int grow = grow0 + m * 16 + lr;
            float v0 = acc[n][m][0] + b4.x;
            float v1 = acc[n][m][1] + b4.y;
            float v2 = acc[n][m][2] + b4.z;
            float v3 = acc[n][m][3] + b4.w;
            if (FUSE == 2) {
                v0 = fast_gelu(v0); v1 = fast_gelu(v1);
                v2 = fast_gelu(v2); v3 = fast_gelu(v3);
            }
            if (FUSE == 1) {
                const float4 rr = *(const float4*)&res[(size_t)grow * N + gcol];
                float4 o = make_float4(v0 + rr.x, v1 + rr.y, v2 + rr.z, v3 + rr.w);
                *(float4*)&((float*)Cout)[(size_t)grow * N + gcol] = o;
            } else {
                uint2 o;
                o.x = pkbf2(v0, v1);
                o.y = pkbf2(v2, v3);
                *(uint2*)&((ushort*)Cout)[(size_t)grow * N + gcol] = o;
            }
        }
    }
}

// ---------------- MFMA windowed attention + fused LePE ----------------
// swapped-QK, no-max softmax, in-register P redistribution via 8 shfls
// (no P LDS round-trip), XOR-swizzled K tile, setprio around MFMA clusters.
__device__ __forceinline__ int wrow(int branch, int b, int wi, int n) {
    if (branch) return b * 3136 + wi * 392 + n;
    int ii = n / 7;
    return b * 3136 + ii * 56 + wi * 7 + (n - ii * 7);
}

__global__ __launch_bounds__(512, 2) void attn_kernel(
    const ushort* __restrict__ qkv,   // bf16 [M,768]
    const float* __restrict__ c0w, const float* __restrict__ c0b,
    const float* __restrict__ c1w, const float* __restrict__ c1b,
    ushort* __restrict__ att)         // bf16 [M,256]
{
    __shared__ __align__(16) ushort Kh[2 * 400 * 16];  // 25,600B, XOR-swizzled (bit3^=(n>>2)&1)
    __shared__ __align__(16) ushort Vt[32][424];       // 27,136B (pitch 848B -> 2-way banks)
    __shared__ float  CwS[9][32];
    __shared__ float  CbS[32];

    int bid    = blockIdx.x;
    int branch = bid >> 8;
    int rem    = bid & 255;
    int head   = rem & 3;
    int win    = rem >> 2;
    int b  = win >> 3, wi = win & 7;
    int c0 = branch * 128 + head * 32;
    const float* cw = branch ? c1w : c0w;
    const float* cb = branch ? c1b : c0b;
    int tid = threadIdx.x;

    if (tid < 288) {
        int tap = tid >> 5, d = tid & 31;
        CwS[tap][d] = cw[tap * 128 + head * 32 + d];
    } else if (tid < 320) {
        CbS[tid - 288] = cb[head * 32 + (tid - 288)];
    }
    // ---- stage K: 400 rows x 16 d, XOR-swizzled; rows >=392 zero ----
    for (int e = tid; e < 1600; e += 512) {
        int n = e >> 2, quad = e & 3;
        uint4 v = make_uint4(0u, 0u, 0u, 0u);
        if (n < 392) {
            int gr = wrow(branch, b, wi, n);
            v = *(const uint4*)(qkv + (size_t)gr * 768 + 256 + c0 + quad * 8);
        }
        int idx = ((quad >> 1) * 6400 + n * 16 + (quad & 1) * 8) ^ (((n >> 2) & 1) << 3);
        *(uint4*)&Kh[idx] = v;
    }
    // ---- stage V transposed ----
    for (int e = tid; e < 1568; e += 512) {
        int n = e >> 2, quad = e & 3;
        int gr = wrow(branch, b, wi, n);
        uint4 v = *(const uint4*)(qkv + (size_t)gr * 768 + 512 + c0 + quad * 8);
        const ushort* us = (const ushort*)&v;
        #pragma unroll
        for (int j = 0; j < 8; ++j) Vt[quad * 8 + j][n] = us[j];
    }
    for (int e = tid; e < 1024; e += 512) {
        int d = e >> 5, k = 392 + (e & 31);
        Vt[d][k] = 0;
    }
    __syncthreads();

    int wv = tid >> 6, lane = tid & 63;
    int lr = lane & 15, lg = lane >> 4;
    constexpr float kSc = 0.17677669529663689f * 1.4426950408889634f;  // scale*log2(e)
    int Hsp = branch ? 7 : 56, Wsp = branch ? 56 : 7;
    int kidx = (((lg >> 1) * 6400) + lr * 16 + (lg & 1) * 8) ^ (((lr >> 2) & 1) << 3);
    const ushort* Kbase = &Kh[kidx];
    // shfl sources for P redistribution: dst (lr,lg) needs k in [8lg, 8lg+8)
    int sA = lr + ((2 * lg) & 3) * 16;
    int sB = lr + ((2 * lg + 1) & 3) * 16;
    bool loP = (lg < 2);

    for (int qt = wv; qt < 25; qt += 8) {
        int q0 = qt * 16;
        int qn = q0 + lr; if (qn > 391) qn = 391;
        int qr = wrow(branch, b, wi, qn);
        s16x8 qf = *(const s16x8*)(qkv + (size_t)qr * 768 + c0 + lg * 8);

        f32x4 o0 = {0.f, 0.f, 0.f, 0.f}, o1 = {0.f, 0.f, 0.f, 0.f};
        float psum = 0.0f;

        auto do_chunk = [&](int c, bool last) {
            f32x4 z = {0.f, 0.f, 0.f, 0.f};
            s16x8 kf0 = *(const s16x8*)&Kbase[c * 512];
            __builtin_amdgcn_s_setprio(1);
            f32x4 s0 = __builtin_amdgcn_mfma_f32_16x16x32_bf16(kf0, qf, z, 0, 0, 0);
            f32x4 s1 = z;
            if (!last) {
                s16x8 kf1 = *(const s16x8*)&Kbase[c * 512 + 256];
                s1 = __builtin_amdgcn_mfma_f32_16x16x32_bf16(kf1, qf, z, 0, 0, 0);
            }
            __builtin_amdgcn_s_setprio(0);
            float p0[4], p1[4];
            #pragma unroll
            for (int r = 0; r < 4; ++r) {
                p0[r] = exp2f(s0[r] * kSc);
                p1[r] = last ? 0.0f : exp2f(s1[r] * kSc);
            }
            if (last && !loP) {   // k_local >= 8 -> key >= 392: masked
                #pragma unroll
                for (int r = 0; r < 4; ++r) p0[r] = 0.0f;
            }
            #pragma unroll
            for (int r = 0; r < 4; ++r) psum += p0[r] + p1[r];
            unsigned A0 = pkbf2(p0[0], p0[1]), A1 = pkbf2(p0[2], p0[3]);
            unsigned B0 = pkbf2(p1[0], p1[1]), B1 = pkbf2(p1[2], p1[3]);
            unsigned a0A = __shfl(A0, sA), a1A = __shfl(A1, sA);
            unsigned b0A = __shfl(B0, sA), b1A = __shfl(B1, sA);
            unsigned a0B = __shfl(A0, sB), a1B = __shfl(A1, sB);
            unsigned b0B = __shfl(B0, sB), b1B = __shfl(B1, sB);
            union { unsigned u[4]; s16x8 v; } pu;
            pu.u[0] = loP ? a0A : b0A;
            pu.u[1] = loP ? a1A : b1A;
            pu.u[2] = loP ? a0B : b0B;
            pu.u[3] = loP ? a1B : b1B;
            s16x8 v0 = *(const s16x8*)&Vt[lr][c * 32 + lg * 8];
            s16x8 v1 = *(const s16x8*)&Vt[16 + lr][c * 32 + lg * 8];
            __builtin_amdgcn_s_setprio(1);
            o0 = __builtin_amdgcn_mfma_f32_16x16x32_bf16(pu.v, v0, o0, 0, 0, 0);
            o1 = __builtin_amdgcn_mfma_f32_16x16x32_bf16(pu.v, v1, o1, 0, 0, 0);
            __builtin_amdgcn_s_setprio(0);
        };

        for (int c = 0; c < 12; ++c) do_chunk(c, false);
        do_chunk(12, true);

        // finalize l per q (lane holds partial for q=lr): sum over the 4 lg groups
        psum += __shfl_xor(psum, 16);
        psum += __shfl_xor(psum, 32);
        float linv[4];
        #pragma unroll
        for (int r = 0; r < 4; ++r)
            linv[r] = 1.0f / __shfl(psum, lg * 4 + r);
        #pragma unroll
        for (int r = 0; r < 4; ++r) { o0[r] *= linv[r]; o1[r] *= linv[r]; }

        // LePE conv + bias + store  (o0[r]: q = q0+lg*4+r, channel lr; o1: channel 16+lr)
        #pragma unroll
        for (int r = 0; r < 4; ++r) {
            int q = q0 + lg * 4 + r;
            if (q >= 392) continue;
            int ii = branch ? (q / 56) : (q / 7);
            int jj = q - ii * Wsp;
            float a0 = o0[r], a1 = o1[r];
            #pragma unroll
            for (int kh = 0; kh < 3; ++kh) {
                int i2 = ii + kh - 1;
                if ((unsigned)i2 >= (unsigned)Hsp) continue;
                #pragma unroll
                for (int kw = 0; kw < 3; ++kw) {
                    int j2 = jj + kw - 1;
                    if ((unsigned)j2 >= (unsigned)Wsp) continue;
                    int pos = i2 * Wsp + j2;
                    a0 += CwS[kh * 3 + kw][lr]      * bf2f(Vt[lr][pos]);
                    a1 += CwS[kh * 3 + kw][16 + lr] * bf2f(Vt[16 + lr][pos]);
                }
            }
            a0 += CbS[lr]; a1 += CbS[16 + lr];
            int gr = wrow(branch, b, wi, q);
            att[(size_t)gr * 256 + branch * 128 + head * 32 + lr]      = f2bf(a0);
            att[(size_t)gr * 256 + branch * 128 + head * 32 + 16 + lr] = f2bf(a1);
        }
    }
}

// ---------------- launcher ----------------
extern "C" void kernel_launch(void* const* d_in, const int* in_sizes, int n_in,
                              void* d_out, int out_size, void* d_ws, size_t ws_size,
                              hipStream_t stream)
{
    const float* x      = (const float*)d_in[0];
    const float* n1g    = (const float*)d_in[3];
    const float* n1b    = (const float*)d_in[4];
    const float* qkv_w  = (const float*)d_in[5];
    const float* proj_w = (const float*)d_in[6];
    const float* proj_b = (const float*)d_in[7];
    const float* c0w    = (const float*)d_in[8];
    const float* c0b    = (const float*)d_in[9];
    const float* c1w    = (const float*)d_in[10];
    const float* c1b    = (const float*)d_in[11];
    const float* n2g    = (const float*)d_in[12];
    const float* n2b    = (const float*)d_in[13];
    const float* fc1_w  = (const float*)d_in[14];
    const float* fc1_b  = (const float*)d_in[15];
    const float* fc2_w  = (const float*)d_in[16];
    const float* fc2_b  = (const float*)d_in[17];
    float* out = (float*)d_out;

    char* ws = (char*)d_ws;
    const size_t SZ_BF = (size_t)MROWS * C_DIM * 2;   // 12,845,056
    ushort* img  = (ushort*)(ws);
    ushort* att  = (ushort*)(ws + SZ_BF);
    ushort* big  = (ushort*)(ws + 2 * SZ_BF);               // qkv [M,768] / hidden [M,1024]
    char*   wbase = ws + 2 * SZ_BF + (size_t)MROWS * HID * 2;
    ushort* qkvT = (ushort*)(wbase);                        // [768][256]
    ushort* projT= (ushort*)(wbase +  393216);              // [256][256]
    ushort* fc1T = (ushort*)(wbase +  393216 + 131072);     // [1024][256]
    ushort* fc2T = (ushort*)(wbase +  393216 + 131072 + 524288); // [256][1024]

    wcvt_all<<<192, 256, 0, stream>>>(qkv_w, proj_w, fc1_w, fc2_w, qkvT, projT, fc1T, fc2T);

    // 1. LN1 -> img (bf16)
    ln_kernel<<<MROWS / 4, 256, 0, stream>>>(x, n1g, n1b, img);
    // 2. qkv = img @ qkv_w  (bf16 out)
    gemm_bf16<0><<<196 * 6, 256, 0, stream>>>(
        img, qkvT, nullptr, nullptr, big, MROWS, 768, 256, 6);
    // 3. attention + LePE -> att (bf16)
    attn_kernel<<<512, 512, 0, stream>>>(big, c0w, c0b, c1w, c1b, att);
    // 4. xr = x + att @ proj_w + proj_b -> d_out (f32)
    gemm_bf16<1><<<196 * 2, 256, 0, stream>>>(
        att, projT, proj_b, x, out, MROWS, 256, 256, 2);
    // 5. LN2 -> img (bf16)
    ln_kernel<<<MROWS / 4, 256, 0, stream>>>(out, n2g, n2b, img);
    // 6. hidden = gelu(img @ fc1_w + fc1_b) (bf16)
    gemm_bf16<2><<<196 * 8, 256, 0, stream>>>(
        img, fc1T, fc1_b, nullptr, big, MROWS, HID, 256, 8);
    // 7. out = xr + hidden @ fc2_w + fc2_b (f32, in-place residual)
    gemm_bf16<1><<<196 * 2, 256, 0, stream>>>(
        big, fc2T, fc2_b, out, out, MROWS, 256, 1024, 2);
}